// Round 7
// baseline (39.443 us; speedup 1.0000x reference)
//
#include <hip/hip_runtime.h>
#include <math.h>

#define HALF_LOG_2PI_F 0.9189385332046727f

typedef float f32x4 __attribute__((ext_vector_type(4)));

// ---------------------------------------------------------------------------
// Fused kernel: every block redundantly computes the per-feature quadratic
// coefficients (deterministic — identical fixed-order arithmetic in every
// block), then streams rows. One wave per row-pair, 2 rows interleaved for
// MLP, A/B cached in registers, reduction = interleaved wave shuffles only.
//   NI = D / 256; wave handles rows (r, r+1), grid-stride by 2*total_waves.
// LDS: 3*D floats (deg, A, B).
// ---------------------------------------------------------------------------
template <int NI>
__global__ __launch_bounds__(256) void clt_fused(
        const float* __restrict__ x,
        const float* __restrict__ rp,
        const int* __restrict__ edges,
        float* __restrict__ out,
        int D, int E, int N, int total_waves) {
    extern __shared__ __align__(16) float smem[];
    float* sdeg = smem;          // [D]
    float* As   = smem + D;      // [D]
    float* Bs   = smem + 2 * D;  // [D]

    const int tid = threadIdx.x;

    // ---- per-block prep (redundant, deterministic) ----
    for (int k = tid; k < D; k += 256) sdeg[k] = 0.0f;
    __syncthreads();
    for (int e = tid; e < E; e += 256) {
        atomicAdd(&sdeg[edges[2 * e]], 1.0f);      // integer-valued: exact
        atomicAdd(&sdeg[edges[2 * e + 1]], 1.0f);
    }
    __syncthreads();

    float local_c = 0.0f;
    for (int k = tid; k < D; k += 256) {
        float m = tanhf(rp[k]) * 2.0f;
        float sx = rp[D + k];
        float s = fmaxf(sx, 0.0f) + log1pf(expf(-fabsf(sx))) + 1e-6f;
        float inv_s2 = 1.0f / (s * s);
        float deg = sdeg[k];
        As[k] = deg * (-0.5f * inv_s2);
        Bs[k] = deg * (m * inv_s2);
        local_c += deg * (-0.5f * m * m * inv_s2 - logf(s) - HALF_LOG_2PI_F);
    }
#pragma unroll
    for (int off = 32; off > 0; off >>= 1)
        local_c += __shfl_down(local_c, off, 64);
    __shared__ float wsum[4];
    if ((tid & 63) == 0) wsum[tid >> 6] = local_c;
    __syncthreads();                                   // publishes As/Bs too
    const float c = wsum[0] + wsum[1] + wsum[2] + wsum[3];

    // ---- load A/B fragments into registers (reused for all rows) ----
    const int lane = tid & 63;
    const f32x4* Av = (const f32x4*)As;
    const f32x4* Bv = (const f32x4*)Bs;
    f32x4 a4[NI], b4[NI];
#pragma unroll
    for (int i = 0; i < NI; ++i) {
        a4[i] = Av[i * 64 + lane];
        b4[i] = Bv[i * 64 + lane];
    }

    // ---- stream rows: 2 per iteration ----
    const int gwave = blockIdx.x * 4 + (tid >> 6);
    for (int r = gwave * 2; r < N; r += total_waves * 2) {
        const f32x4* xv0 = (const f32x4*)(x + (size_t)r * (size_t)D);
        const f32x4* xv1 = (const f32x4*)(x + (size_t)(r + 1) * (size_t)D);
        float p0 = 0.0f, q0 = 0.0f, p1 = 0.0f, q1 = 0.0f;
#pragma unroll
        for (int i = 0; i < NI; ++i) {
            f32x4 x0 = __builtin_nontemporal_load(&xv0[i * 64 + lane]);
            f32x4 x1 = __builtin_nontemporal_load(&xv1[i * 64 + lane]);
            p0 += x0.x * fmaf(a4[i].x, x0.x, b4[i].x);
            q0 += x0.y * fmaf(a4[i].y, x0.y, b4[i].y);
            p0 += x0.z * fmaf(a4[i].z, x0.z, b4[i].z);
            q0 += x0.w * fmaf(a4[i].w, x0.w, b4[i].w);
            p1 += x1.x * fmaf(a4[i].x, x1.x, b4[i].x);
            q1 += x1.y * fmaf(a4[i].y, x1.y, b4[i].y);
            p1 += x1.z * fmaf(a4[i].z, x1.z, b4[i].z);
            q1 += x1.w * fmaf(a4[i].w, x1.w, b4[i].w);
        }
        float acc0 = p0 + q0;
        float acc1 = p1 + q1;
#pragma unroll
        for (int off = 32; off > 0; off >>= 1) {
            acc0 += __shfl_down(acc0, off, 64);
            acc1 += __shfl_down(acc1, off, 64);
        }
        if (lane == 0) {
            out[r] = acc0 + c;
            out[r + 1] = acc1 + c;   // N even; r is even
        }
    }
}

// ---------------------------------------------------------------------------
// Fallback path (any D): prep kernel + block-per-row kernel, as in R2.
// ---------------------------------------------------------------------------
__global__ void clt_prep_kernel(const float* __restrict__ rp,
                                const int* __restrict__ edges,
                                float* __restrict__ A,
                                float* __restrict__ B,
                                float* __restrict__ csum,
                                int D, int E) {
    extern __shared__ float sdeg[];
    for (int k = threadIdx.x; k < D; k += blockDim.x) sdeg[k] = 0.0f;
    __syncthreads();
    for (int e = threadIdx.x; e < E; e += blockDim.x) {
        atomicAdd(&sdeg[edges[2 * e]], 1.0f);
        atomicAdd(&sdeg[edges[2 * e + 1]], 1.0f);
    }
    __syncthreads();
    float local_c = 0.0f;
    for (int k = threadIdx.x; k < D; k += blockDim.x) {
        float m = tanhf(rp[k]) * 2.0f;
        float sx = rp[D + k];
        float s = fmaxf(sx, 0.0f) + log1pf(expf(-fabsf(sx))) + 1e-6f;
        float inv_s2 = 1.0f / (s * s);
        float deg = sdeg[k];
        A[k] = deg * (-0.5f * inv_s2);
        B[k] = deg * (m * inv_s2);
        local_c += deg * (-0.5f * m * m * inv_s2 - logf(s) - HALF_LOG_2PI_F);
    }
    __shared__ float wsum[16];
    for (int off = 32; off > 0; off >>= 1)
        local_c += __shfl_down(local_c, off, 64);
    if ((threadIdx.x & 63) == 0) wsum[threadIdx.x >> 6] = local_c;
    __syncthreads();
    if (threadIdx.x == 0) {
        float t = 0.0f;
        int nw = (blockDim.x + 63) >> 6;
        for (int w = 0; w < nw; ++w) t += wsum[w];
        *csum = t;
    }
}

__global__ __launch_bounds__(256) void clt_row_generic(
        const float* __restrict__ x,
        const float* __restrict__ A,
        const float* __restrict__ B,
        const float* __restrict__ csum,
        float* __restrict__ out,
        int D) {
    const int row = blockIdx.x;
    float acc = 0.0f;
    for (int k = threadIdx.x; k < D; k += blockDim.x) {
        float xs = x[(size_t)row * (size_t)D + k];
        acc += xs * fmaf(A[k], xs, B[k]);
    }
    for (int off = 32; off > 0; off >>= 1)
        acc += __shfl_down(acc, off, 64);
    __shared__ float wsum[4];
    if ((threadIdx.x & 63) == 0) wsum[threadIdx.x >> 6] = acc;
    __syncthreads();
    if (threadIdx.x == 0)
        out[row] = wsum[0] + wsum[1] + wsum[2] + wsum[3] + *csum;
}

extern "C" void kernel_launch(void* const* d_in, const int* in_sizes, int n_in,
                              void* d_out, int out_size, void* d_ws, size_t ws_size,
                              hipStream_t stream) {
    const float* x     = (const float*)d_in[0];
    const float* rp    = (const float*)d_in[1];
    const int*   edges = (const int*)d_in[2];
    float* out = (float*)d_out;

    const int D = in_sizes[1] / 2;       // 2048
    const int E = in_sizes[2] / 2;       // D-1
    const int N = out_size;              // 16384 rows

    const int NI = D / 256;
    const bool fast = (D % 256 == 0) && (N % 2 == 0) &&
                      (NI == 2 || NI == 4 || NI == 8 || NI == 16);
    if (fast) {
        const int blocks = 512;                 // 2 blocks/CU, perfectly balanced:
        const int total_waves = blocks * 4;     // 2048 waves x 8 rows = 16384
        const size_t lds = (size_t)3 * D * sizeof(float);
        switch (NI) {
            case 2:  clt_fused<2><<<blocks, 256, lds, stream>>>(x, rp, edges, out, D, E, N, total_waves); break;
            case 4:  clt_fused<4><<<blocks, 256, lds, stream>>>(x, rp, edges, out, D, E, N, total_waves); break;
            case 8:  clt_fused<8><<<blocks, 256, lds, stream>>>(x, rp, edges, out, D, E, N, total_waves); break;
            default: clt_fused<16><<<blocks, 256, lds, stream>>>(x, rp, edges, out, D, E, N, total_waves); break;
        }
    } else {
        float* A    = (float*)d_ws;
        float* B    = A + D;
        float* csum = B + D;
        clt_prep_kernel<<<1, 1024, D * sizeof(float), stream>>>(rp, edges, A, B, csum, D, E);
        clt_row_generic<<<N, 256, 0, stream>>>(x, A, B, csum, out, D);
    }
}